// Round 10
// baseline (585.182 us; speedup 1.0000x reference)
//
#include <hip/hip_runtime.h>
#include <hip/hip_bf16.h>
#include <math.h>

#define B_  256
#define S_  200
#define F_  10
#define T_  100
#define E_  128
#define H_  256
#define G4  1024   // 4*H
#define P1_ 512
#define P2_ 128

typedef __attribute__((ext_vector_type(8))) short short8;
typedef __attribute__((ext_vector_type(4))) float f32x4;
typedef _Float16 half2f __attribute__((ext_vector_type(2)));

#if __has_builtin(__builtin_amdgcn_fdot2)
#define FDOT2(w2, h2, acc) __builtin_amdgcn_fdot2((w2), (h2), (acc), false)
#else
#define FDOT2(w2, h2, acc) ((acc) + (float)((w2)[0]) * (float)((h2)[0]) + (float)((w2)[1]) * (float)((h2)[1]))
#endif
#define BCH2(u) __builtin_bit_cast(half2f, (u))
#define DO4(W0, W1, W2, W3, HH) \
    a = FDOT2(BCH2(W0), BCH2((HH).x), a); \
    a = FDOT2(BCH2(W1), BCH2((HH).y), a); \
    a = FDOT2(BCH2(W2), BCH2((HH).z), a); \
    a = FDOT2(BCH2(W3), BCH2((HH).w), a);

// scan W placement (kpair rows of 1024 uints): LDS | VGPR | streamed
#define NL_ 36
#define NR_ 80
#define NS_ 12

__device__ __forceinline__ float sigf(float x) { return 1.0f / (1.0f + expf(-x)); }
__device__ __forceinline__ ushort f2bf(float f) {
    __hip_bfloat16 v = __float2bfloat16(f);
    return *(ushort*)&v;
}
__device__ __forceinline__ ushort f2h(float f) {
    _Float16 h = (_Float16)f;
    return __builtin_bit_cast(ushort, h);
}

__global__ __launch_bounds__(256) void k_bsum(const float* __restrict__ bi,
                                              const float* __restrict__ bh,
                                              float* __restrict__ bs) {
    int i = blockIdx.x * 256 + threadIdx.x;
    if (i < G4) bs[i] = bi[i] + bh[i];
}

// W (R x C) f32 -> WT (C x R) bf16. grid (C/32, R/32), 256 thr.
__global__ __launch_bounds__(256) void k_tr_bf16(const float* __restrict__ W,
                                                 ushort* __restrict__ WT,
                                                 int R, int C) {
    __shared__ float t[32][33];
    int c0 = blockIdx.x * 32, r0 = blockIdx.y * 32;
    int lc = threadIdx.x & 31, lr = threadIdx.x >> 5;
    #pragma unroll
    for (int i = 0; i < 4; ++i)
        t[lr + 8 * i][lc] = W[(long)(r0 + lr + 8 * i) * C + c0 + lc];
    __syncthreads();
    #pragma unroll
    for (int i = 0; i < 4; ++i)
        WT[(long)(c0 + lr + 8 * i) * R + r0 + lc] = f2bf(t[lc][lr + 8 * i]);
}

// W_hh (1024 x 256) f32 -> WPu: k-pair-interleaved fp16.
// WPu[kp*1024 + c] = pack(f16(W[c][2kp]), f16(W[c][2kp+1])), kp=0..127.
__global__ __launch_bounds__(256) void k_prep_wp(const float* __restrict__ W,
                                                 uint* __restrict__ WPu) {
    __shared__ float t[32][33];
    int k0 = blockIdx.x * 32, c0 = blockIdx.y * 32;
    int lk = threadIdx.x & 31, lc8 = threadIdx.x >> 5;
    #pragma unroll
    for (int i = 0; i < 4; ++i)
        t[lc8 + 8 * i][lk] = W[(long)(c0 + lc8 + 8 * i) * 256 + k0 + lk];
    __syncthreads();
    int kpl = threadIdx.x >> 4;   // 0..15
    int ccl = threadIdx.x & 15;   // 0..15
    #pragma unroll
    for (int hf = 0; hf < 2; ++hf) {
        int c = ccl + 16 * hf;
        uint lo = f2h(t[c][2 * kpl]);
        uint hi = f2h(t[c][2 * kpl + 1]);
        WPu[(long)(k0 / 2 + kpl) * G4 + c0 + c] = lo | (hi << 16);
    }
}

__global__ __launch_bounds__(256) void k_cvt_bf16(const float* __restrict__ W,
                                                  ushort* __restrict__ O, int n) {
    int i = blockIdx.x * 256 + threadIdx.x;
    if (i < n) O[i] = f2bf(W[i]);
}

// one block per (b,s); 128 threads = one e-dim each; bf16 out
__global__ __launch_bounds__(128) void k_gather(const int* __restrict__ x,
                                                const float* __restrict__ emb,
                                                ushort* __restrict__ e) {
    int bs = blockIdx.x;
    int t  = threadIdx.x;
    const int* xr = x + (long)bs * F_;
    float acc = 0.f;
    #pragma unroll
    for (int f = 0; f < F_; ++f) acc += emb[(long)xr[f] * E_ + t];
    e[(long)bs * E_ + t] = f2bf(acc * (1.0f / F_));
}

// ---------------- bf16 MFMA GEMM (unchanged) ----------------
template<int ACT, int OUTBF>
__global__ __launch_bounds__(256) void k_gemm_mfma(
    const ushort* __restrict__ A, int rowDiv, long sOuter, long sInner,
    const ushort* __restrict__ Bm,
    const float* __restrict__ bias,
    const float* __restrict__ rowAdd, int rowAddDiv,
    void* __restrict__ Cout, int N, int K)
{
    constexpr int LDT = 40;
    __shared__ ushort Al[128 * LDT];
    __shared__ ushort Bl[128 * LDT];
    int tid = threadIdx.x;
    int n0 = blockIdx.x * 128;
    int m0 = blockIdx.y * 128;

    int rA = tid >> 2, qA = tid & 3;
    int m_lo = m0 + rA, m_hi = m_lo + 64;
    long a0 = (long)(m_lo / rowDiv) * sOuter + (long)(m_lo % rowDiv) * sInner + qA * 8;
    long a1 = (long)(m_hi / rowDiv) * sOuter + (long)(m_hi % rowDiv) * sInner + qA * 8;
    const ushort* b0p = Bm + (long)(n0 + rA) * K + qA * 8;
    const ushort* b1p = Bm + (long)(n0 + rA + 64) * K + qA * 8;

    int lane = tid & 63, wave = tid >> 6;
    int wr = wave >> 1, wc = wave & 1;
    int lrow = lane & 15, lkh = lane >> 4;

    const f32x4 fz = {0.f, 0.f, 0.f, 0.f};
    f32x4 acc[4][4];
    #pragma unroll
    for (int i = 0; i < 4; ++i)
        #pragma unroll
        for (int j = 0; j < 4; ++j) acc[i][j] = fz;

    int nk = K >> 5;
    for (int kc = 0; kc < nk; ++kc) {
        uint4 va0 = *(const uint4*)(A + a0 + kc * 32);
        uint4 va1 = *(const uint4*)(A + a1 + kc * 32);
        uint4 vb0 = *(const uint4*)(b0p + kc * 32);
        uint4 vb1 = *(const uint4*)(b1p + kc * 32);
        *(uint4*)&Al[rA * LDT + qA * 8]        = va0;
        *(uint4*)&Al[(rA + 64) * LDT + qA * 8] = va1;
        *(uint4*)&Bl[rA * LDT + qA * 8]        = vb0;
        *(uint4*)&Bl[(rA + 64) * LDT + qA * 8] = vb1;
        __syncthreads();
        short8 af[4], bfr[4];
        #pragma unroll
        for (int mi = 0; mi < 4; ++mi)
            af[mi] = *(const short8*)&Al[(wr * 64 + mi * 16 + lrow) * LDT + lkh * 8];
        #pragma unroll
        for (int ni = 0; ni < 4; ++ni)
            bfr[ni] = *(const short8*)&Bl[(wc * 64 + ni * 16 + lrow) * LDT + lkh * 8];
        #pragma unroll
        for (int mi = 0; mi < 4; ++mi)
            #pragma unroll
            for (int ni = 0; ni < 4; ++ni)
                acc[mi][ni] = __builtin_amdgcn_mfma_f32_16x16x32_bf16(
                    af[mi], bfr[ni], acc[mi][ni], 0, 0, 0);
        __syncthreads();
    }
    #pragma unroll
    for (int mi = 0; mi < 4; ++mi) {
        #pragma unroll
        for (int r = 0; r < 4; ++r) {
            int m = m0 + wr * 64 + mi * 16 + lkh * 4 + r;
            long rowoff = rowAdd ? (long)(m / rowAddDiv) * N : 0;
            #pragma unroll
            for (int ni = 0; ni < 4; ++ni) {
                int n = n0 + wc * 64 + ni * 16 + lrow;
                float v = acc[mi][ni][r];
                if (bias)   v += bias[n];
                if (rowAdd) v += rowAdd[rowoff + n];
                if (ACT)    v = fmaxf(v, 0.f);
                if (OUTBF) ((ushort*)Cout)[(long)m * N + n] = f2bf(v);
                else       ((float*)Cout)[(long)m * N + n] = v;
            }
        }
    }
}

// ---------------- fp32 GEMM (kept for small hhdec) ----------------
template<int BT, int ACT>
__global__ __launch_bounds__(256) void k_gemm(
    const float* __restrict__ A, int rowDiv, long sOuter, long sInner,
    const float* __restrict__ Bm,
    const float* __restrict__ bias,
    const float* __restrict__ rowAdd, int rowAddDiv,
    float* __restrict__ C, int M, int N, int K)
{
    __shared__ float Al[32 * 66];
    __shared__ float Bl[32 * 130];
    int tid = threadIdx.x;
    int n0 = blockIdx.x * 128;
    int m0 = blockIdx.y * 64;
    int cA = tid & 31;
    int rA = tid >> 5;
    long rb[8];
    #pragma unroll
    for (int i = 0; i < 8; ++i) {
        int m = m0 + rA + 8 * i;
        rb[i] = (long)(m / rowDiv) * sOuter + (long)(m % rowDiv) * sInner;
    }
    int tr = tid >> 5, tc = tid & 31;
    float acc[8][4] = {};
    int nk = K >> 5;
    for (int kc = 0; kc < nk; ++kc) {
        #pragma unroll
        for (int i = 0; i < 8; ++i)
            Al[cA * 66 + rA + 8 * i] = A[rb[i] + kc * 32 + cA];
        if (BT) {
            #pragma unroll
            for (int i = 0; i < 16; ++i) {
                int lin = tid + 256 * i;
                int n = lin >> 5, k = lin & 31;
                Bl[k * 130 + n] = Bm[(long)(n0 + n) * K + kc * 32 + k];
            }
        } else {
            #pragma unroll
            for (int i = 0; i < 16; ++i) {
                int lin = tid + 256 * i;
                int k = lin >> 7, n = lin & 127;
                Bl[k * 130 + n] = Bm[(long)(kc * 32 + k) * N + n0 + n];
            }
        }
        __syncthreads();
        #pragma unroll 4
        for (int k = 0; k < 32; ++k) {
            float a_[8], b_[4];
            *(float2*)&a_[0] = *(float2*)&Al[k * 66 + tr * 8];
            *(float2*)&a_[2] = *(float2*)&Al[k * 66 + tr * 8 + 2];
            *(float2*)&a_[4] = *(float2*)&Al[k * 66 + tr * 8 + 4];
            *(float2*)&a_[6] = *(float2*)&Al[k * 66 + tr * 8 + 6];
            *(float2*)&b_[0] = *(float2*)&Bl[k * 130 + tc * 4];
            *(float2*)&b_[2] = *(float2*)&Bl[k * 130 + tc * 4 + 2];
            #pragma unroll
            for (int i = 0; i < 8; ++i)
                #pragma unroll
                for (int j = 0; j < 4; ++j)
                    acc[i][j] += a_[i] * b_[j];
        }
        __syncthreads();
    }
    #pragma unroll
    for (int i = 0; i < 8; ++i) {
        int m = m0 + tr * 8 + i;
        int n = n0 + tc * 4;
        float4 v;
        float* vp = &v.x;
        #pragma unroll
        for (int j = 0; j < 4; ++j) {
            float t = acc[i][j];
            if (bias)   t += bias[n + j];
            if (rowAdd) t += rowAdd[(long)(m / rowAddDiv) * N + n + j];
            if (ACT == 1) t = fmaxf(t, 0.f);
            vp[j] = t;
        }
        *(float4*)&C[(long)m * N + n] = v;
    }
}

// Persistent LSTM scan, W fully resident: one gate-column per thread.
// 1024 threads/block, one block per batch row. W kpair rows (packed fp16):
//   kp 0..NL_-1       in LDS (loaded once)
//   kp NL_..NL_+NR_-1 in VGPRs (wr[], static indexing)
//   kp NL_+NR_..127   streamed from L2 (loads issued at step top)
// __launch_bounds__(1024, 4): 4 waves/EU = 1 block/CU (LDS forces that anyway)
// -> VGPR cap 512/thread so wr[NR_] stays in registers (r9 spilled at cap 64).
__global__ __launch_bounds__(1024, 4) void k_lstm_scan(
    const float* __restrict__ Xg, const uint* __restrict__ WPu,
    float* __restrict__ hN, float* __restrict__ cN)
{
    extern __shared__ __align__(16) char smem[];
    uint*   Wl    = (uint*)smem;                    // NL_*1024 uints (144 KB)
    float*  act_s = (float*)(smem + NL_ * 4096);    // 1024 f32 (4 KB)
    uint*   h16u  = (uint*)(act_s + G4);            // 128 uints (packed f16 h)
    ushort* h16   = (ushort*)h16u;
    int tid = threadIdx.x;
    int b   = blockIdx.x;

    // one-time LDS W fill (coalesced)
    for (int i = tid; i < NL_ * 1024; i += 1024)
        Wl[i] = WPu[(long)(i >> 10) * G4 + (i & 1023)];
    // one-time VGPR W fill (row-coalesced dword loads)
    uint wr[NR_];
    #pragma unroll
    for (int i = 0; i < NR_; ++i)
        wr[i] = WPu[(long)(NL_ + i) * G4 + tid];
    if (tid < 128) h16u[tid] = 0;
    float c_r = 0.f;
    __syncthreads();

    int isTanh = (tid >> 8) == 2;                   // uniform per wave
    const float* xgp = Xg + (long)b * T_ * G4 + tid;

    for (int t = 0; t < T_; ++t) {
        float xv = xgp[(long)t * G4];               // independent prefetch
        uint ws[NS_];
        #pragma unroll
        for (int i = 0; i < NS_; ++i)               // streamed rows: issue early
            ws[i] = WPu[(long)(NL_ + NR_ + i) * G4 + tid];
        float a = 0.f;
        #pragma unroll
        for (int c4 = 0; c4 < NL_ / 4; ++c4) {      // LDS rows
            uint4 hh = *(const uint4*)(h16u + 4 * c4);
            uint w0 = Wl[(4 * c4 + 0) * 1024 + tid];
            uint w1 = Wl[(4 * c4 + 1) * 1024 + tid];
            uint w2 = Wl[(4 * c4 + 2) * 1024 + tid];
            uint w3 = Wl[(4 * c4 + 3) * 1024 + tid];
            DO4(w0, w1, w2, w3, hh);
        }
        #pragma unroll
        for (int c4 = 0; c4 < NR_ / 4; ++c4) {      // VGPR rows
            uint4 hh = *(const uint4*)(h16u + NL_ + 4 * c4);
            DO4(wr[4 * c4], wr[4 * c4 + 1], wr[4 * c4 + 2], wr[4 * c4 + 3], hh);
        }
        #pragma unroll
        for (int c4 = 0; c4 < NS_ / 4; ++c4) {      // streamed rows (loads done)
            uint4 hh = *(const uint4*)(h16u + NL_ + NR_ + 4 * c4);
            DO4(ws[4 * c4], ws[4 * c4 + 1], ws[4 * c4 + 2], ws[4 * c4 + 3], hh);
        }
        float g = a + xv;
        act_s[tid] = isTanh ? tanhf(g) : sigf(g);
        __syncthreads();
        if (tid < H_) {
            float cn = act_s[H_ + tid] * c_r + act_s[tid] * act_s[2 * H_ + tid];
            c_r = cn;
            float h = act_s[3 * H_ + tid] * tanhf(cn);
            h16[tid] = f2h(h);
            if (t == T_ - 1) {
                hN[(long)b * H_ + tid] = h;
                cN[(long)b * H_ + tid] = c_r;
            }
        }
        __syncthreads();
    }
}

__global__ __launch_bounds__(256) void k_dec_cell(const float* __restrict__ G,
                                                  const float* __restrict__ cNb,
                                                  ushort* __restrict__ hdec) {
    long idx = (long)blockIdx.x * 256 + threadIdx.x;
    int m = (int)(idx >> 8);
    int j = (int)(idx & 255);
    int b = m / T_;
    const float* g = G + (long)m * G4 + j;
    float gi = g[0], gf = g[H_], gg = g[2 * H_], go = g[3 * H_];
    float cv = sigf(gf) * cNb[(long)b * H_ + j] + sigf(gi) * tanhf(gg);
    hdec[idx] = f2bf(sigf(go) * tanhf(cv));
}

__global__ __launch_bounds__(256) void k_mlp3(const float* __restrict__ z2,
                                              const float* __restrict__ W3,
                                              const float* __restrict__ b3,
                                              float* __restrict__ out) {
    int wave = threadIdx.x >> 6, lane = threadIdx.x & 63;
    int m = blockIdx.x * 4 + wave;
    const float* zr = z2 + (long)m * P2_;
    float s = zr[lane] * W3[lane] + zr[64 + lane] * W3[64 + lane];
    #pragma unroll
    for (int off = 32; off > 0; off >>= 1) s += __shfl_down(s, off);
    if (lane == 0) out[m] = sigf(s + b3[0]);
}

extern "C" void kernel_launch(void* const* d_in, const int* in_sizes, int n_in,
                              void* d_out, int out_size, void* d_ws, size_t ws_size,
                              hipStream_t stream)
{
    const int*   x    = (const int*)d_in[0];
    const float* emb  = (const float*)d_in[1];
    const float* W_ih = (const float*)d_in[2];
    const float* W_hh = (const float*)d_in[3];
    const float* b_ih = (const float*)d_in[4];
    const float* b_hh = (const float*)d_in[5];
    const float* W1   = (const float*)d_in[6];
    const float* b1   = (const float*)d_in[7];
    const float* W2   = (const float*)d_in[8];
    const float* b2   = (const float*)d_in[9];
    const float* W3   = (const float*)d_in[10];
    const float* b3   = (const float*)d_in[11];
    float* out = (float*)d_out;

    float* ws = (float*)d_ws;
    ushort* ebf  = (ushort*)ws;                 // B*S*E bf16 (3,276,800 f)
    float* Xg    = ws + 3276800;                // 26,214,400 f
    float* bsum  = Xg + 26214400;               // 1024
    float* hN    = bsum + 1024;                 // 65,536
    float* cN    = hN + 65536;                  // 65,536
    float* hhdec = cN + 65536;                  // 262,144
    uint*  WPu   = (uint*)(hhdec + 262144);     // 131,072 uints (512 KB)
    ushort* Wihb = (ushort*)(WPu + 131072);     // 131,072 ush
    ushort* W1T  = Wihb + 131072;               // 131,072 ush
    ushort* W2T  = W1T + 131072;                // 65,536 ush
    // reuse (stream-ordered):
    ushort* hdec_bf = ebf;
    ushort* z1b  = (ushort*)Xg;
    float*  z2   = Xg + 6553600;

    k_bsum<<<4, 256, 0, stream>>>(b_ih, b_hh, bsum);
    k_prep_wp<<<dim3(8, 32), 256, 0, stream>>>(W_hh, WPu);
    k_tr_bf16<<<dim3(16, 8),  256, 0, stream>>>(W1, W1T, H_, P1_);
    k_tr_bf16<<<dim3(4, 16),  256, 0, stream>>>(W2, W2T, P1_, P2_);
    k_cvt_bf16<<<512, 256, 0, stream>>>(W_ih, Wihb, G4 * E_);
    k_gather<<<B_ * S_, 128, 0, stream>>>(x, emb, ebf);

    // Xg = e_hist @ W_ih^T + bsum
    k_gemm_mfma<0, 0><<<dim3(G4 / 128, (B_ * T_) / 128), 256, 0, stream>>>(
        ebf, T_, (long)S_ * E_, (long)E_, Wihb, bsum, nullptr, 1,
        Xg, G4, E_);

    // persistent scan: W resident in LDS+VGPR, 12 rows streamed
    size_t scan_smem = (size_t)NL_ * 4096 + G4 * sizeof(float) + 128 * sizeof(uint);
    k_lstm_scan<<<B_, 1024, scan_smem, stream>>>(Xg, WPu, hN, cN);

    // hhdec = hN @ W_hh^T + bsum (fp32, tiny)
    k_gemm<1, 0><<<dim3(G4 / 128, B_ / 64), 256, 0, stream>>>(
        hN, B_, 0L, (long)H_, W_hh, bsum, nullptr, 1,
        hhdec, B_, G4, H_);

    // Gdec = e_tgt @ W_ih^T + hhdec[b]
    k_gemm_mfma<0, 0><<<dim3(G4 / 128, (B_ * T_) / 128), 256, 0, stream>>>(
        ebf + T_ * E_, T_, (long)S_ * E_, (long)E_, Wihb, nullptr, hhdec, T_,
        Xg, G4, E_);

    // decode cell -> hdec_bf
    k_dec_cell<<<(B_ * T_ * H_) / 256, 256, 0, stream>>>(Xg, cN, hdec_bf);

    // z1 = relu(hdec @ W1 + b1) -> bf16
    k_gemm_mfma<1, 1><<<dim3(P1_ / 128, (B_ * T_) / 128), 256, 0, stream>>>(
        hdec_bf, B_ * T_, 0L, (long)H_, W1T, b1, nullptr, 1,
        z1b, P1_, H_);

    // z2 = relu(z1 @ W2 + b2) -> f32
    k_gemm_mfma<1, 0><<<dim3(P2_ / 128, (B_ * T_) / 128), 256, 0, stream>>>(
        z1b, B_ * T_, 0L, (long)P1_, W2T, b2, nullptr, 1,
        z2, P2_, P1_);

    // out = sigmoid(z2 . W3 + b3)
    k_mlp3<<<(B_ * T_) / 4, 256, 0, stream>>>(z2, W3, b3, out);
}

// Round 11
// 531.593 us; speedup vs baseline: 1.1008x; 1.1008x over previous
//
#include <hip/hip_runtime.h>
#include <hip/hip_bf16.h>
#include <math.h>

#define B_  256
#define S_  200
#define F_  10
#define T_  100
#define E_  128
#define H_  256
#define G4  1024   // 4*H
#define P1_ 512
#define P2_ 128

typedef __attribute__((ext_vector_type(8))) short short8;
typedef __attribute__((ext_vector_type(4))) float f32x4;
typedef _Float16 half2f __attribute__((ext_vector_type(2)));

#if __has_builtin(__builtin_amdgcn_fdot2)
#define FDOT2(w2, h2, acc) __builtin_amdgcn_fdot2((w2), (h2), (acc), false)
#else
#define FDOT2(w2, h2, acc) ((acc) + (float)((w2)[0]) * (float)((h2)[0]) + (float)((w2)[1]) * (float)((h2)[1]))
#endif
#define BCH2(u) __builtin_bit_cast(half2f, (u))

// scan W placement (kpair rows of 1024 uints): 36 in LDS, 92 in VGPRs (x2 cols)
#define NL2_ 36
#define NV2_ 92

__device__ __forceinline__ float sigf(float x) { return 1.0f / (1.0f + expf(-x)); }
__device__ __forceinline__ ushort f2bf(float f) {
    __hip_bfloat16 v = __float2bfloat16(f);
    return *(ushort*)&v;
}
__device__ __forceinline__ ushort f2h(float f) {
    _Float16 h = (_Float16)f;
    return __builtin_bit_cast(ushort, h);
}

__global__ __launch_bounds__(256) void k_bsum(const float* __restrict__ bi,
                                              const float* __restrict__ bh,
                                              float* __restrict__ bs) {
    int i = blockIdx.x * 256 + threadIdx.x;
    if (i < G4) bs[i] = bi[i] + bh[i];
}

// W (R x C) f32 -> WT (C x R) bf16. grid (C/32, R/32), 256 thr.
__global__ __launch_bounds__(256) void k_tr_bf16(const float* __restrict__ W,
                                                 ushort* __restrict__ WT,
                                                 int R, int C) {
    __shared__ float t[32][33];
    int c0 = blockIdx.x * 32, r0 = blockIdx.y * 32;
    int lc = threadIdx.x & 31, lr = threadIdx.x >> 5;
    #pragma unroll
    for (int i = 0; i < 4; ++i)
        t[lr + 8 * i][lc] = W[(long)(r0 + lr + 8 * i) * C + c0 + lc];
    __syncthreads();
    #pragma unroll
    for (int i = 0; i < 4; ++i)
        WT[(long)(c0 + lr + 8 * i) * R + r0 + lc] = f2bf(t[lc][lr + 8 * i]);
}

// W_hh (1024 x 256) f32 -> WPu: k-pair-interleaved fp16.
// WPu[kp*1024 + c] = pack(f16(W[c][2kp]), f16(W[c][2kp+1])), kp=0..127.
__global__ __launch_bounds__(256) void k_prep_wp(const float* __restrict__ W,
                                                 uint* __restrict__ WPu) {
    __shared__ float t[32][33];
    int k0 = blockIdx.x * 32, c0 = blockIdx.y * 32;
    int lk = threadIdx.x & 31, lc8 = threadIdx.x >> 5;
    #pragma unroll
    for (int i = 0; i < 4; ++i)
        t[lc8 + 8 * i][lk] = W[(long)(c0 + lc8 + 8 * i) * 256 + k0 + lk];
    __syncthreads();
    int kpl = threadIdx.x >> 4;   // 0..15
    int ccl = threadIdx.x & 15;   // 0..15
    #pragma unroll
    for (int hf = 0; hf < 2; ++hf) {
        int c = ccl + 16 * hf;
        uint lo = f2h(t[c][2 * kpl]);
        uint hi = f2h(t[c][2 * kpl + 1]);
        WPu[(long)(k0 / 2 + kpl) * G4 + c0 + c] = lo | (hi << 16);
    }
}

__global__ __launch_bounds__(256) void k_cvt_bf16(const float* __restrict__ W,
                                                  ushort* __restrict__ O, int n) {
    int i = blockIdx.x * 256 + threadIdx.x;
    if (i < n) O[i] = f2bf(W[i]);
}

// one block per (b,s); 128 threads = one e-dim each; bf16 out
__global__ __launch_bounds__(128) void k_gather(const int* __restrict__ x,
                                                const float* __restrict__ emb,
                                                ushort* __restrict__ e) {
    int bs = blockIdx.x;
    int t  = threadIdx.x;
    const int* xr = x + (long)bs * F_;
    float acc = 0.f;
    #pragma unroll
    for (int f = 0; f < F_; ++f) acc += emb[(long)xr[f] * E_ + t];
    e[(long)bs * E_ + t] = f2bf(acc * (1.0f / F_));
}

// ---------------- bf16 MFMA GEMM (unchanged) ----------------
template<int ACT, int OUTBF>
__global__ __launch_bounds__(256) void k_gemm_mfma(
    const ushort* __restrict__ A, int rowDiv, long sOuter, long sInner,
    const ushort* __restrict__ Bm,
    const float* __restrict__ bias,
    const float* __restrict__ rowAdd, int rowAddDiv,
    void* __restrict__ Cout, int N, int K)
{
    constexpr int LDT = 40;
    __shared__ ushort Al[128 * LDT];
    __shared__ ushort Bl[128 * LDT];
    int tid = threadIdx.x;
    int n0 = blockIdx.x * 128;
    int m0 = blockIdx.y * 128;

    int rA = tid >> 2, qA = tid & 3;
    int m_lo = m0 + rA, m_hi = m_lo + 64;
    long a0 = (long)(m_lo / rowDiv) * sOuter + (long)(m_lo % rowDiv) * sInner + qA * 8;
    long a1 = (long)(m_hi / rowDiv) * sOuter + (long)(m_hi % rowDiv) * sInner + qA * 8;
    const ushort* b0p = Bm + (long)(n0 + rA) * K + qA * 8;
    const ushort* b1p = Bm + (long)(n0 + rA + 64) * K + qA * 8;

    int lane = tid & 63, wave = tid >> 6;
    int wr = wave >> 1, wc = wave & 1;
    int lrow = lane & 15, lkh = lane >> 4;

    const f32x4 fz = {0.f, 0.f, 0.f, 0.f};
    f32x4 acc[4][4];
    #pragma unroll
    for (int i = 0; i < 4; ++i)
        #pragma unroll
        for (int j = 0; j < 4; ++j) acc[i][j] = fz;

    int nk = K >> 5;
    for (int kc = 0; kc < nk; ++kc) {
        uint4 va0 = *(const uint4*)(A + a0 + kc * 32);
        uint4 va1 = *(const uint4*)(A + a1 + kc * 32);
        uint4 vb0 = *(const uint4*)(b0p + kc * 32);
        uint4 vb1 = *(const uint4*)(b1p + kc * 32);
        *(uint4*)&Al[rA * LDT + qA * 8]        = va0;
        *(uint4*)&Al[(rA + 64) * LDT + qA * 8] = va1;
        *(uint4*)&Bl[rA * LDT + qA * 8]        = vb0;
        *(uint4*)&Bl[(rA + 64) * LDT + qA * 8] = vb1;
        __syncthreads();
        short8 af[4], bfr[4];
        #pragma unroll
        for (int mi = 0; mi < 4; ++mi)
            af[mi] = *(const short8*)&Al[(wr * 64 + mi * 16 + lrow) * LDT + lkh * 8];
        #pragma unroll
        for (int ni = 0; ni < 4; ++ni)
            bfr[ni] = *(const short8*)&Bl[(wc * 64 + ni * 16 + lrow) * LDT + lkh * 8];
        #pragma unroll
        for (int mi = 0; mi < 4; ++mi)
            #pragma unroll
            for (int ni = 0; ni < 4; ++ni)
                acc[mi][ni] = __builtin_amdgcn_mfma_f32_16x16x32_bf16(
                    af[mi], bfr[ni], acc[mi][ni], 0, 0, 0);
        __syncthreads();
    }
    #pragma unroll
    for (int mi = 0; mi < 4; ++mi) {
        #pragma unroll
        for (int r = 0; r < 4; ++r) {
            int m = m0 + wr * 64 + mi * 16 + lkh * 4 + r;
            long rowoff = rowAdd ? (long)(m / rowAddDiv) * N : 0;
            #pragma unroll
            for (int ni = 0; ni < 4; ++ni) {
                int n = n0 + wc * 64 + ni * 16 + lrow;
                float v = acc[mi][ni][r];
                if (bias)   v += bias[n];
                if (rowAdd) v += rowAdd[rowoff + n];
                if (ACT)    v = fmaxf(v, 0.f);
                if (OUTBF) ((ushort*)Cout)[(long)m * N + n] = f2bf(v);
                else       ((float*)Cout)[(long)m * N + n] = v;
            }
        }
    }
}

// ---------------- fp32 GEMM (kept for small hhdec) ----------------
template<int BT, int ACT>
__global__ __launch_bounds__(256) void k_gemm(
    const float* __restrict__ A, int rowDiv, long sOuter, long sInner,
    const float* __restrict__ Bm,
    const float* __restrict__ bias,
    const float* __restrict__ rowAdd, int rowAddDiv,
    float* __restrict__ C, int M, int N, int K)
{
    __shared__ float Al[32 * 66];
    __shared__ float Bl[32 * 130];
    int tid = threadIdx.x;
    int n0 = blockIdx.x * 128;
    int m0 = blockIdx.y * 64;
    int cA = tid & 31;
    int rA = tid >> 5;
    long rb[8];
    #pragma unroll
    for (int i = 0; i < 8; ++i) {
        int m = m0 + rA + 8 * i;
        rb[i] = (long)(m / rowDiv) * sOuter + (long)(m % rowDiv) * sInner;
    }
    int tr = tid >> 5, tc = tid & 31;
    float acc[8][4] = {};
    int nk = K >> 5;
    for (int kc = 0; kc < nk; ++kc) {
        #pragma unroll
        for (int i = 0; i < 8; ++i)
            Al[cA * 66 + rA + 8 * i] = A[rb[i] + kc * 32 + cA];
        if (BT) {
            #pragma unroll
            for (int i = 0; i < 16; ++i) {
                int lin = tid + 256 * i;
                int n = lin >> 5, k = lin & 31;
                Bl[k * 130 + n] = Bm[(long)(n0 + n) * K + kc * 32 + k];
            }
        } else {
            #pragma unroll
            for (int i = 0; i < 16; ++i) {
                int lin = tid + 256 * i;
                int k = lin >> 7, n = lin & 127;
                Bl[k * 130 + n] = Bm[(long)(kc * 32 + k) * N + n0 + n];
            }
        }
        __syncthreads();
        #pragma unroll 4
        for (int k = 0; k < 32; ++k) {
            float a_[8], b_[4];
            *(float2*)&a_[0] = *(float2*)&Al[k * 66 + tr * 8];
            *(float2*)&a_[2] = *(float2*)&Al[k * 66 + tr * 8 + 2];
            *(float2*)&a_[4] = *(float2*)&Al[k * 66 + tr * 8 + 4];
            *(float2*)&a_[6] = *(float2*)&Al[k * 66 + tr * 8 + 6];
            *(float2*)&b_[0] = *(float2*)&Bl[k * 130 + tc * 4];
            *(float2*)&b_[2] = *(float2*)&Bl[k * 130 + tc * 4 + 2];
            #pragma unroll
            for (int i = 0; i < 8; ++i)
                #pragma unroll
                for (int j = 0; j < 4; ++j)
                    acc[i][j] += a_[i] * b_[j];
        }
        __syncthreads();
    }
    #pragma unroll
    for (int i = 0; i < 8; ++i) {
        int m = m0 + tr * 8 + i;
        int n = n0 + tc * 4;
        float4 v;
        float* vp = &v.x;
        #pragma unroll
        for (int j = 0; j < 4; ++j) {
            float t = acc[i][j];
            if (bias)   t += bias[n + j];
            if (rowAdd) t += rowAdd[(long)(m / rowAddDiv) * N + n + j];
            if (ACT == 1) t = fmaxf(t, 0.f);
            vp[j] = t;
        }
        *(float4*)&C[(long)m * N + n] = v;
    }
}

// Persistent LSTM scan, W fully CU-resident. 512 threads/block (2 waves/SIMD
// -> 256-VGPR cap), one block per batch row. Each thread owns TWO gate cols
// (tid, tid+512). W kpair rows (packed fp16): rows 0..NL2_-1 in LDS (loaded
// once); rows NL2_..127 in VGPRs (wrA/wrB, static indexing). Nothing streamed.
__global__ __launch_bounds__(512, 2) void k_lstm_scan(
    const float* __restrict__ Xg, const uint* __restrict__ WPu,
    float* __restrict__ hN, float* __restrict__ cN)
{
    extern __shared__ __align__(16) char smem[];
    uint*   Wl    = (uint*)smem;                    // NL2_*1024 uints (144 KB)
    float*  act_s = (float*)(smem + NL2_ * 4096);   // 1024 f32 (4 KB)
    uint*   h16u  = (uint*)(act_s + G4);            // 128 uints (packed f16 h)
    ushort* h16   = (ushort*)h16u;
    int tid = threadIdx.x;          // 0..511
    int b   = blockIdx.x;
    int cB  = tid + 512;

    // one-time LDS W fill (coalesced)
    for (int i = tid; i < NL2_ * 1024; i += 512)
        Wl[i] = WPu[(long)(i >> 10) * G4 + (i & 1023)];
    // one-time VGPR W fill (row-coalesced dword loads)
    uint wrA[NV2_], wrB[NV2_];
    #pragma unroll
    for (int i = 0; i < NV2_; ++i) {
        wrA[i] = WPu[(long)(NL2_ + i) * G4 + tid];
        wrB[i] = WPu[(long)(NL2_ + i) * G4 + cB];
    }
    if (tid < 128) h16u[tid] = 0;
    float c_r = 0.f;
    __syncthreads();

    int isTanhB = (tid >> 8) == 0;   // cB in [512,768) -> tanh; wave-uniform
    const float* xgp = Xg + (long)b * T_ * G4;

    for (int t = 0; t < T_; ++t) {
        float xvA = xgp[(long)t * G4 + tid];
        float xvB = xgp[(long)t * G4 + cB];
        float aA = 0.f, aB = 0.f;
        #pragma unroll
        for (int r4 = 0; r4 < NL2_ / 4; ++r4) {         // LDS rows (36)
            uint4 hh = *(const uint4*)(h16u + 4 * r4);
            uint a0 = Wl[(4 * r4 + 0) * 1024 + tid], b0 = Wl[(4 * r4 + 0) * 1024 + cB];
            uint a1 = Wl[(4 * r4 + 1) * 1024 + tid], b1 = Wl[(4 * r4 + 1) * 1024 + cB];
            uint a2 = Wl[(4 * r4 + 2) * 1024 + tid], b2 = Wl[(4 * r4 + 2) * 1024 + cB];
            uint a3 = Wl[(4 * r4 + 3) * 1024 + tid], b3 = Wl[(4 * r4 + 3) * 1024 + cB];
            aA = FDOT2(BCH2(a0), BCH2(hh.x), aA); aB = FDOT2(BCH2(b0), BCH2(hh.x), aB);
            aA = FDOT2(BCH2(a1), BCH2(hh.y), aA); aB = FDOT2(BCH2(b1), BCH2(hh.y), aB);
            aA = FDOT2(BCH2(a2), BCH2(hh.z), aA); aB = FDOT2(BCH2(b2), BCH2(hh.z), aB);
            aA = FDOT2(BCH2(a3), BCH2(hh.w), aA); aB = FDOT2(BCH2(b3), BCH2(hh.w), aB);
        }
        #pragma unroll
        for (int r4 = 0; r4 < NV2_ / 4; ++r4) {         // VGPR rows (92)
            uint4 hh = *(const uint4*)(h16u + NL2_ + 4 * r4);
            aA = FDOT2(BCH2(wrA[4 * r4 + 0]), BCH2(hh.x), aA);
            aB = FDOT2(BCH2(wrB[4 * r4 + 0]), BCH2(hh.x), aB);
            aA = FDOT2(BCH2(wrA[4 * r4 + 1]), BCH2(hh.y), aA);
            aB = FDOT2(BCH2(wrB[4 * r4 + 1]), BCH2(hh.y), aB);
            aA = FDOT2(BCH2(wrA[4 * r4 + 2]), BCH2(hh.z), aA);
            aB = FDOT2(BCH2(wrB[4 * r4 + 2]), BCH2(hh.z), aB);
            aA = FDOT2(BCH2(wrA[4 * r4 + 3]), BCH2(hh.w), aA);
            aB = FDOT2(BCH2(wrB[4 * r4 + 3]), BCH2(hh.w), aB);
        }
        act_s[tid] = sigf(aA + xvA);                    // cols 0..511: i,f gates
        float gB = aB + xvB;
        act_s[cB] = isTanhB ? tanhf(gB) : sigf(gB);     // cols 512..1023: g,o
        __syncthreads();
        if (tid < H_) {
            float cn = act_s[H_ + tid] * c_r + act_s[tid] * act_s[2 * H_ + tid];
            c_r = cn;
            float h = act_s[3 * H_ + tid] * tanhf(cn);
            h16[tid] = f2h(h);
            if (t == T_ - 1) {
                hN[(long)b * H_ + tid] = h;
                cN[(long)b * H_ + tid] = c_r;
            }
        }
        __syncthreads();
    }
}

__global__ __launch_bounds__(256) void k_dec_cell(const float* __restrict__ G,
                                                  const float* __restrict__ cNb,
                                                  ushort* __restrict__ hdec) {
    long idx = (long)blockIdx.x * 256 + threadIdx.x;
    int m = (int)(idx >> 8);
    int j = (int)(idx & 255);
    int b = m / T_;
    const float* g = G + (long)m * G4 + j;
    float gi = g[0], gf = g[H_], gg = g[2 * H_], go = g[3 * H_];
    float cv = sigf(gf) * cNb[(long)b * H_ + j] + sigf(gi) * tanhf(gg);
    hdec[idx] = f2bf(sigf(go) * tanhf(cv));
}

__global__ __launch_bounds__(256) void k_mlp3(const float* __restrict__ z2,
                                              const float* __restrict__ W3,
                                              const float* __restrict__ b3,
                                              float* __restrict__ out) {
    int wave = threadIdx.x >> 6, lane = threadIdx.x & 63;
    int m = blockIdx.x * 4 + wave;
    const float* zr = z2 + (long)m * P2_;
    float s = zr[lane] * W3[lane] + zr[64 + lane] * W3[64 + lane];
    #pragma unroll
    for (int off = 32; off > 0; off >>= 1) s += __shfl_down(s, off);
    if (lane == 0) out[m] = sigf(s + b3[0]);
}

extern "C" void kernel_launch(void* const* d_in, const int* in_sizes, int n_in,
                              void* d_out, int out_size, void* d_ws, size_t ws_size,
                              hipStream_t stream)
{
    const int*   x    = (const int*)d_in[0];
    const float* emb  = (const float*)d_in[1];
    const float* W_ih = (const float*)d_in[2];
    const float* W_hh = (const float*)d_in[3];
    const float* b_ih = (const float*)d_in[4];
    const float* b_hh = (const float*)d_in[5];
    const float* W1   = (const float*)d_in[6];
    const float* b1   = (const float*)d_in[7];
    const float* W2   = (const float*)d_in[8];
    const float* b2   = (const float*)d_in[9];
    const float* W3   = (const float*)d_in[10];
    const float* b3   = (const float*)d_in[11];
    float* out = (float*)d_out;

    float* ws = (float*)d_ws;
    ushort* ebf  = (ushort*)ws;                 // B*S*E bf16 (3,276,800 f)
    float* Xg    = ws + 3276800;                // 26,214,400 f
    float* bsum  = Xg + 26214400;               // 1024
    float* hN    = bsum + 1024;                 // 65,536
    float* cN    = hN + 65536;                  // 65,536
    float* hhdec = cN + 65536;                  // 262,144
    uint*  WPu   = (uint*)(hhdec + 262144);     // 131,072 uints (512 KB)
    ushort* Wihb = (ushort*)(WPu + 131072);     // 131,072 ush
    ushort* W1T  = Wihb + 131072;               // 131,072 ush
    ushort* W2T  = W1T + 131072;                // 65,536 ush
    // reuse (stream-ordered):
    ushort* hdec_bf = ebf;
    ushort* z1b  = (ushort*)Xg;
    float*  z2   = Xg + 6553600;

    k_bsum<<<4, 256, 0, stream>>>(b_ih, b_hh, bsum);
    k_prep_wp<<<dim3(8, 32), 256, 0, stream>>>(W_hh, WPu);
    k_tr_bf16<<<dim3(16, 8),  256, 0, stream>>>(W1, W1T, H_, P1_);
    k_tr_bf16<<<dim3(4, 16),  256, 0, stream>>>(W2, W2T, P1_, P2_);
    k_cvt_bf16<<<512, 256, 0, stream>>>(W_ih, Wihb, G4 * E_);
    k_gather<<<B_ * S_, 128, 0, stream>>>(x, emb, ebf);

    // Xg = e_hist @ W_ih^T + bsum
    k_gemm_mfma<0, 0><<<dim3(G4 / 128, (B_ * T_) / 128), 256, 0, stream>>>(
        ebf, T_, (long)S_ * E_, (long)E_, Wihb, bsum, nullptr, 1,
        Xg, G4, E_);

    // persistent scan: W fully resident (LDS 36 rows + VGPR 92 rows x 2 cols)
    size_t scan_smem = (size_t)NL2_ * 4096 + G4 * sizeof(float) + 128 * sizeof(uint);
    k_lstm_scan<<<B_, 512, scan_smem, stream>>>(Xg, WPu, hN, cN);

    // hhdec = hN @ W_hh^T + bsum (fp32, tiny)
    k_gemm<1, 0><<<dim3(G4 / 128, B_ / 64), 256, 0, stream>>>(
        hN, B_, 0L, (long)H_, W_hh, bsum, nullptr, 1,
        hhdec, B_, G4, H_);

    // Gdec = e_tgt @ W_ih^T + hhdec[b]
    k_gemm_mfma<0, 0><<<dim3(G4 / 128, (B_ * T_) / 128), 256, 0, stream>>>(
        ebf + T_ * E_, T_, (long)S_ * E_, (long)E_, Wihb, nullptr, hhdec, T_,
        Xg, G4, E_);

    // decode cell -> hdec_bf
    k_dec_cell<<<(B_ * T_ * H_) / 256, 256, 0, stream>>>(Xg, cN, hdec_bf);

    // z1 = relu(hdec @ W1 + b1) -> bf16
    k_gemm_mfma<1, 1><<<dim3(P1_ / 128, (B_ * T_) / 128), 256, 0, stream>>>(
        hdec_bf, B_ * T_, 0L, (long)H_, W1T, b1, nullptr, 1,
        z1b, P1_, H_);

    // z2 = relu(z1 @ W2 + b2) -> f32
    k_gemm_mfma<1, 0><<<dim3(P2_ / 128, (B_ * T_) / 128), 256, 0, stream>>>(
        z1b, B_ * T_, 0L, (long)P1_, W2T, b2, nullptr, 1,
        z2, P2_, P1_);

    // out = sigmoid(z2 . W3 + b3)
    k_mlp3<<<(B_ * T_) / 4, 256, 0, stream>>>(z2, W3, b3, out);
}

// Round 12
// 473.565 us; speedup vs baseline: 1.2357x; 1.1225x over previous
//
#include <hip/hip_runtime.h>
#include <hip/hip_bf16.h>
#include <math.h>

#define B_  256
#define S_  200
#define F_  10
#define T_  100
#define E_  128
#define H_  256
#define G4  1024   // 4*H
#define P1_ 512
#define P2_ 128

typedef __attribute__((ext_vector_type(8))) short short8;
typedef __attribute__((ext_vector_type(4))) float f32x4;
typedef _Float16 half2f __attribute__((ext_vector_type(2)));

#if __has_builtin(__builtin_amdgcn_fdot2)
#define FDOT2(w2, h2, acc) __builtin_amdgcn_fdot2((w2), (h2), (acc), false)
#else
#define FDOT2(w2, h2, acc) ((acc) + (float)((w2)[0]) * (float)((h2)[0]) + (float)((w2)[1]) * (float)((h2)[1]))
#endif
#define BCH2(u) __builtin_bit_cast(half2f, (u))

// scan W placement (kpair rows of 1024 uints): 36 in LDS, 92 in VGPRs (x2 cols)
#define NL2_ 36
#define NV2_ 92

__device__ __forceinline__ float sigf(float x) { return 1.0f / (1.0f + expf(-x)); }
__device__ __forceinline__ float bf2f(ushort u) { return __uint_as_float(((uint)u) << 16); }
__device__ __forceinline__ ushort f2bf(float f) {
    __hip_bfloat16 v = __float2bfloat16(f);
    return *(ushort*)&v;
}
__device__ __forceinline__ ushort f2h(float f) {
    _Float16 h = (_Float16)f;
    return __builtin_bit_cast(ushort, h);
}

__global__ __launch_bounds__(256) void k_bsum(const float* __restrict__ bi,
                                              const float* __restrict__ bh,
                                              float* __restrict__ bs) {
    int i = blockIdx.x * 256 + threadIdx.x;
    if (i < G4) bs[i] = bi[i] + bh[i];
}

// W (R x C) f32 -> WT (C x R) bf16. grid (C/32, R/32), 256 thr.
__global__ __launch_bounds__(256) void k_tr_bf16(const float* __restrict__ W,
                                                 ushort* __restrict__ WT,
                                                 int R, int C) {
    __shared__ float t[32][33];
    int c0 = blockIdx.x * 32, r0 = blockIdx.y * 32;
    int lc = threadIdx.x & 31, lr = threadIdx.x >> 5;
    #pragma unroll
    for (int i = 0; i < 4; ++i)
        t[lr + 8 * i][lc] = W[(long)(r0 + lr + 8 * i) * C + c0 + lc];
    __syncthreads();
    #pragma unroll
    for (int i = 0; i < 4; ++i)
        WT[(long)(c0 + lr + 8 * i) * R + r0 + lc] = f2bf(t[lc][lr + 8 * i]);
}

// W_hh (1024 x 256) f32 -> WPu: k-pair-interleaved fp16.
// WPu[kp*1024 + c] = pack(f16(W[c][2kp]), f16(W[c][2kp+1])), kp=0..127.
__global__ __launch_bounds__(256) void k_prep_wp(const float* __restrict__ W,
                                                 uint* __restrict__ WPu) {
    __shared__ float t[32][33];
    int k0 = blockIdx.x * 32, c0 = blockIdx.y * 32;
    int lk = threadIdx.x & 31, lc8 = threadIdx.x >> 5;
    #pragma unroll
    for (int i = 0; i < 4; ++i)
        t[lc8 + 8 * i][lk] = W[(long)(c0 + lc8 + 8 * i) * 256 + k0 + lk];
    __syncthreads();
    int kpl = threadIdx.x >> 4;   // 0..15
    int ccl = threadIdx.x & 15;   // 0..15
    #pragma unroll
    for (int hf = 0; hf < 2; ++hf) {
        int c = ccl + 16 * hf;
        uint lo = f2h(t[c][2 * kpl]);
        uint hi = f2h(t[c][2 * kpl + 1]);
        WPu[(long)(k0 / 2 + kpl) * G4 + c0 + c] = lo | (hi << 16);
    }
}

__global__ __launch_bounds__(256) void k_cvt_bf16(const float* __restrict__ W,
                                                  ushort* __restrict__ O, int n) {
    int i = blockIdx.x * 256 + threadIdx.x;
    if (i < n) O[i] = f2bf(W[i]);
}

// one block per (b,s); 128 threads = one e-dim each; bf16 out
__global__ __launch_bounds__(128) void k_gather(const int* __restrict__ x,
                                                const float* __restrict__ emb,
                                                ushort* __restrict__ e) {
    int bs = blockIdx.x;
    int t  = threadIdx.x;
    const int* xr = x + (long)bs * F_;
    float acc = 0.f;
    #pragma unroll
    for (int f = 0; f < F_; ++f) acc += emb[(long)xr[f] * E_ + t];
    e[(long)bs * E_ + t] = f2bf(acc * (1.0f / F_));
}

// ---------------- bf16 MFMA GEMM (unchanged) ----------------
template<int ACT, int OUTBF>
__global__ __launch_bounds__(256) void k_gemm_mfma(
    const ushort* __restrict__ A, int rowDiv, long sOuter, long sInner,
    const ushort* __restrict__ Bm,
    const float* __restrict__ bias,
    const float* __restrict__ rowAdd, int rowAddDiv,
    void* __restrict__ Cout, int N, int K)
{
    constexpr int LDT = 40;
    __shared__ ushort Al[128 * LDT];
    __shared__ ushort Bl[128 * LDT];
    int tid = threadIdx.x;
    int n0 = blockIdx.x * 128;
    int m0 = blockIdx.y * 128;

    int rA = tid >> 2, qA = tid & 3;
    int m_lo = m0 + rA, m_hi = m_lo + 64;
    long a0 = (long)(m_lo / rowDiv) * sOuter + (long)(m_lo % rowDiv) * sInner + qA * 8;
    long a1 = (long)(m_hi / rowDiv) * sOuter + (long)(m_hi % rowDiv) * sInner + qA * 8;
    const ushort* b0p = Bm + (long)(n0 + rA) * K + qA * 8;
    const ushort* b1p = Bm + (long)(n0 + rA + 64) * K + qA * 8;

    int lane = tid & 63, wave = tid >> 6;
    int wr = wave >> 1, wc = wave & 1;
    int lrow = lane & 15, lkh = lane >> 4;

    const f32x4 fz = {0.f, 0.f, 0.f, 0.f};
    f32x4 acc[4][4];
    #pragma unroll
    for (int i = 0; i < 4; ++i)
        #pragma unroll
        for (int j = 0; j < 4; ++j) acc[i][j] = fz;

    int nk = K >> 5;
    for (int kc = 0; kc < nk; ++kc) {
        uint4 va0 = *(const uint4*)(A + a0 + kc * 32);
        uint4 va1 = *(const uint4*)(A + a1 + kc * 32);
        uint4 vb0 = *(const uint4*)(b0p + kc * 32);
        uint4 vb1 = *(const uint4*)(b1p + kc * 32);
        *(uint4*)&Al[rA * LDT + qA * 8]        = va0;
        *(uint4*)&Al[(rA + 64) * LDT + qA * 8] = va1;
        *(uint4*)&Bl[rA * LDT + qA * 8]        = vb0;
        *(uint4*)&Bl[(rA + 64) * LDT + qA * 8] = vb1;
        __syncthreads();
        short8 af[4], bfr[4];
        #pragma unroll
        for (int mi = 0; mi < 4; ++mi)
            af[mi] = *(const short8*)&Al[(wr * 64 + mi * 16 + lrow) * LDT + lkh * 8];
        #pragma unroll
        for (int ni = 0; ni < 4; ++ni)
            bfr[ni] = *(const short8*)&Bl[(wc * 64 + ni * 16 + lrow) * LDT + lkh * 8];
        #pragma unroll
        for (int mi = 0; mi < 4; ++mi)
            #pragma unroll
            for (int ni = 0; ni < 4; ++ni)
                acc[mi][ni] = __builtin_amdgcn_mfma_f32_16x16x32_bf16(
                    af[mi], bfr[ni], acc[mi][ni], 0, 0, 0);
        __syncthreads();
    }
    #pragma unroll
    for (int mi = 0; mi < 4; ++mi) {
        #pragma unroll
        for (int r = 0; r < 4; ++r) {
            int m = m0 + wr * 64 + mi * 16 + lkh * 4 + r;
            long rowoff = rowAdd ? (long)(m / rowAddDiv) * N : 0;
            #pragma unroll
            for (int ni = 0; ni < 4; ++ni) {
                int n = n0 + wc * 64 + ni * 16 + lrow;
                float v = acc[mi][ni][r];
                if (bias)   v += bias[n];
                if (rowAdd) v += rowAdd[rowoff + n];
                if (ACT)    v = fmaxf(v, 0.f);
                if (OUTBF) ((ushort*)Cout)[(long)m * N + n] = f2bf(v);
                else       ((float*)Cout)[(long)m * N + n] = v;
            }
        }
    }
}

// ---------------- fp32 GEMM (kept for small hhdec) ----------------
template<int BT, int ACT>
__global__ __launch_bounds__(256) void k_gemm(
    const float* __restrict__ A, int rowDiv, long sOuter, long sInner,
    const float* __restrict__ Bm,
    const float* __restrict__ bias,
    const float* __restrict__ rowAdd, int rowAddDiv,
    float* __restrict__ C, int M, int N, int K)
{
    __shared__ float Al[32 * 66];
    __shared__ float Bl[32 * 130];
    int tid = threadIdx.x;
    int n0 = blockIdx.x * 128;
    int m0 = blockIdx.y * 64;
    int cA = tid & 31;
    int rA = tid >> 5;
    long rb[8];
    #pragma unroll
    for (int i = 0; i < 8; ++i) {
        int m = m0 + rA + 8 * i;
        rb[i] = (long)(m / rowDiv) * sOuter + (long)(m % rowDiv) * sInner;
    }
    int tr = tid >> 5, tc = tid & 31;
    float acc[8][4] = {};
    int nk = K >> 5;
    for (int kc = 0; kc < nk; ++kc) {
        #pragma unroll
        for (int i = 0; i < 8; ++i)
            Al[cA * 66 + rA + 8 * i] = A[rb[i] + kc * 32 + cA];
        if (BT) {
            #pragma unroll
            for (int i = 0; i < 16; ++i) {
                int lin = tid + 256 * i;
                int n = lin >> 5, k = lin & 31;
                Bl[k * 130 + n] = Bm[(long)(n0 + n) * K + kc * 32 + k];
            }
        } else {
            #pragma unroll
            for (int i = 0; i < 16; ++i) {
                int lin = tid + 256 * i;
                int k = lin >> 7, n = lin & 127;
                Bl[k * 130 + n] = Bm[(long)(kc * 32 + k) * N + n0 + n];
            }
        }
        __syncthreads();
        #pragma unroll 4
        for (int k = 0; k < 32; ++k) {
            float a_[8], b_[4];
            *(float2*)&a_[0] = *(float2*)&Al[k * 66 + tr * 8];
            *(float2*)&a_[2] = *(float2*)&Al[k * 66 + tr * 8 + 2];
            *(float2*)&a_[4] = *(float2*)&Al[k * 66 + tr * 8 + 4];
            *(float2*)&a_[6] = *(float2*)&Al[k * 66 + tr * 8 + 6];
            *(float2*)&b_[0] = *(float2*)&Bl[k * 130 + tc * 4];
            *(float2*)&b_[2] = *(float2*)&Bl[k * 130 + tc * 4 + 2];
            #pragma unroll
            for (int i = 0; i < 8; ++i)
                #pragma unroll
                for (int j = 0; j < 4; ++j)
                    acc[i][j] += a_[i] * b_[j];
        }
        __syncthreads();
    }
    #pragma unroll
    for (int i = 0; i < 8; ++i) {
        int m = m0 + tr * 8 + i;
        int n = n0 + tc * 4;
        float4 v;
        float* vp = &v.x;
        #pragma unroll
        for (int j = 0; j < 4; ++j) {
            float t = acc[i][j];
            if (bias)   t += bias[n + j];
            if (rowAdd) t += rowAdd[(long)(m / rowAddDiv) * N + n + j];
            if (ACT == 1) t = fmaxf(t, 0.f);
            vp[j] = t;
        }
        *(float4*)&C[(long)m * N + n] = v;
    }
}

// Persistent LSTM scan, W fully CU-resident. 512 threads/block (2 waves/SIMD
// -> 256-reg cap), one block per batch row. Each thread owns TWO gate cols
// (tid, tid+512). W kpair rows (packed fp16): rows 0..NL2_-1 in LDS stored
// TRANSPOSED [col][36 rows] (stride 144 B, 16B-aligned -> ds_read_b128 of 4
// rows, bank-uniform 8 accesses/bank = optimal); rows NL2_..127 in VGPRs.
__global__ __launch_bounds__(512, 2) void k_lstm_scan(
    const float* __restrict__ Xg, const uint* __restrict__ WPu,
    float* __restrict__ hN, float* __restrict__ cN)
{
    extern __shared__ __align__(16) char smem[];
    uint*   Wl    = (uint*)smem;                    // [1024 cols][NL2_ rows] uints
    float*  act_s = (float*)(smem + NL2_ * 4096);   // 1024 f32 (4 KB)
    uint*   h16u  = (uint*)(act_s + G4);            // 128 uints (packed f16 h)
    ushort* h16   = (ushort*)h16u;
    int tid = threadIdx.x;          // 0..511
    int b   = blockIdx.x;
    int cB  = tid + 512;

    // one-time LDS W fill, transposed (global read coalesced, LDS scatter)
    for (int i = tid; i < NL2_ * 1024; i += 512) {
        int row = i >> 10, col = i & 1023;
        Wl[col * NL2_ + row] = WPu[(long)row * G4 + col];
    }
    // one-time VGPR W fill (row-coalesced dword loads)
    uint wrA[NV2_], wrB[NV2_];
    #pragma unroll
    for (int i = 0; i < NV2_; ++i) {
        wrA[i] = WPu[(long)(NL2_ + i) * G4 + tid];
        wrB[i] = WPu[(long)(NL2_ + i) * G4 + cB];
    }
    if (tid < 128) h16u[tid] = 0;
    float c_r = 0.f;
    __syncthreads();

    int isTanhB = (tid >> 8) == 0;   // cB in [512,768) -> tanh; wave-uniform
    const float* xgp = Xg + (long)b * T_ * G4;
    const uint* wcA = Wl + tid * NL2_;
    const uint* wcB = Wl + (tid + 512) * NL2_;

    for (int t = 0; t < T_; ++t) {
        float xvA = xgp[(long)t * G4 + tid];
        float xvB = xgp[(long)t * G4 + cB];
        float aA = 0.f, aB = 0.f;
        #pragma unroll
        for (int r4 = 0; r4 < NL2_ / 4; ++r4) {         // LDS rows: b128 x2
            uint4 hh = *(const uint4*)(h16u + 4 * r4);
            uint4 wa = *(const uint4*)(wcA + 4 * r4);
            uint4 wb = *(const uint4*)(wcB + 4 * r4);
            aA = FDOT2(BCH2(wa.x), BCH2(hh.x), aA); aB = FDOT2(BCH2(wb.x), BCH2(hh.x), aB);
            aA = FDOT2(BCH2(wa.y), BCH2(hh.y), aA); aB = FDOT2(BCH2(wb.y), BCH2(hh.y), aB);
            aA = FDOT2(BCH2(wa.z), BCH2(hh.z), aA); aB = FDOT2(BCH2(wb.z), BCH2(hh.z), aB);
            aA = FDOT2(BCH2(wa.w), BCH2(hh.w), aA); aB = FDOT2(BCH2(wb.w), BCH2(hh.w), aB);
        }
        #pragma unroll
        for (int r4 = 0; r4 < NV2_ / 4; ++r4) {         // VGPR rows (92)
            uint4 hh = *(const uint4*)(h16u + NL2_ + 4 * r4);
            aA = FDOT2(BCH2(wrA[4 * r4 + 0]), BCH2(hh.x), aA);
            aB = FDOT2(BCH2(wrB[4 * r4 + 0]), BCH2(hh.x), aB);
            aA = FDOT2(BCH2(wrA[4 * r4 + 1]), BCH2(hh.y), aA);
            aB = FDOT2(BCH2(wrB[4 * r4 + 1]), BCH2(hh.y), aB);
            aA = FDOT2(BCH2(wrA[4 * r4 + 2]), BCH2(hh.z), aA);
            aB = FDOT2(BCH2(wrB[4 * r4 + 2]), BCH2(hh.z), aB);
            aA = FDOT2(BCH2(wrA[4 * r4 + 3]), BCH2(hh.w), aA);
            aB = FDOT2(BCH2(wrB[4 * r4 + 3]), BCH2(hh.w), aB);
        }
        act_s[tid] = sigf(aA + xvA);                    // cols 0..511: i,f gates
        float gB = aB + xvB;
        act_s[cB] = isTanhB ? tanhf(gB) : sigf(gB);     // cols 512..1023: g,o
        __syncthreads();
        if (tid < H_) {
            float cn = act_s[H_ + tid] * c_r + act_s[tid] * act_s[2 * H_ + tid];
            c_r = cn;
            float h = act_s[3 * H_ + tid] * tanhf(cn);
            h16[tid] = f2h(h);
            if (t == T_ - 1) {
                hN[(long)b * H_ + tid] = h;
                cN[(long)b * H_ + tid] = c_r;
            }
        }
        __syncthreads();
    }
}

// decode cell, bf16 gate input (Gdec written bf16 by MFMA GEMM)
__global__ __launch_bounds__(256) void k_dec_cell(const ushort* __restrict__ G,
                                                  const float* __restrict__ cNb,
                                                  ushort* __restrict__ hdec) {
    long idx = (long)blockIdx.x * 256 + threadIdx.x;
    int m = (int)(idx >> 8);
    int j = (int)(idx & 255);
    int b = m / T_;
    const ushort* g = G + (long)m * G4 + j;
    float gi = bf2f(g[0]), gf = bf2f(g[H_]);
    float gg = bf2f(g[2 * H_]), go = bf2f(g[3 * H_]);
    float cv = sigf(gf) * cNb[(long)b * H_ + j] + sigf(gi) * tanhf(gg);
    hdec[idx] = f2bf(sigf(go) * tanhf(cv));
}

__global__ __launch_bounds__(256) void k_mlp3(const float* __restrict__ z2,
                                              const float* __restrict__ W3,
                                              const float* __restrict__ b3,
                                              float* __restrict__ out) {
    int wave = threadIdx.x >> 6, lane = threadIdx.x & 63;
    int m = blockIdx.x * 4 + wave;
    const float* zr = z2 + (long)m * P2_;
    float s = zr[lane] * W3[lane] + zr[64 + lane] * W3[64 + lane];
    #pragma unroll
    for (int off = 32; off > 0; off >>= 1) s += __shfl_down(s, off);
    if (lane == 0) out[m] = sigf(s + b3[0]);
}

extern "C" void kernel_launch(void* const* d_in, const int* in_sizes, int n_in,
                              void* d_out, int out_size, void* d_ws, size_t ws_size,
                              hipStream_t stream)
{
    const int*   x    = (const int*)d_in[0];
    const float* emb  = (const float*)d_in[1];
    const float* W_ih = (const float*)d_in[2];
    const float* W_hh = (const float*)d_in[3];
    const float* b_ih = (const float*)d_in[4];
    const float* b_hh = (const float*)d_in[5];
    const float* W1   = (const float*)d_in[6];
    const float* b1   = (const float*)d_in[7];
    const float* W2   = (const float*)d_in[8];
    const float* b2   = (const float*)d_in[9];
    const float* W3   = (const float*)d_in[10];
    const float* b3   = (const float*)d_in[11];
    float* out = (float*)d_out;

    float* ws = (float*)d_ws;
    ushort* ebf  = (ushort*)ws;                 // B*S*E bf16 (3,276,800 f)
    float* Xg    = ws + 3276800;                // 26,214,400 f (encoder, f32)
    float* bsum  = Xg + 26214400;               // 1024
    float* hN    = bsum + 1024;                 // 65,536
    float* cN    = hN + 65536;                  // 65,536
    float* hhdec = cN + 65536;                  // 262,144
    uint*  WPu   = (uint*)(hhdec + 262144);     // 131,072 uints (512 KB)
    ushort* Wihb = (ushort*)(WPu + 131072);     // 131,072 ush
    ushort* W1T  = Wihb + 131072;               // 131,072 ush
    ushort* W2T  = W1T + 131072;                // 65,536 ush
    // reuse (stream-ordered):
    ushort* Gdecb   = (ushort*)Xg;              // decoder gates, bf16 (52 MB)
    ushort* hdec_bf = ebf;                      // after Gdec GEMM, ebf dead
    ushort* z1b  = (ushort*)Xg;                 // after dec_cell, Gdecb dead
    float*  z2   = Xg + 6553600;                // after z1b region

    k_bsum<<<4, 256, 0, stream>>>(b_ih, b_hh, bsum);
    k_prep_wp<<<dim3(8, 32), 256, 0, stream>>>(W_hh, WPu);
    k_tr_bf16<<<dim3(16, 8),  256, 0, stream>>>(W1, W1T, H_, P1_);
    k_tr_bf16<<<dim3(4, 16),  256, 0, stream>>>(W2, W2T, P1_, P2_);
    k_cvt_bf16<<<512, 256, 0, stream>>>(W_ih, Wihb, G4 * E_);
    k_gather<<<B_ * S_, 128, 0, stream>>>(x, emb, ebf);

    // Xg = e_hist @ W_ih^T + bsum  (f32 out; feeds the recurrent scan)
    k_gemm_mfma<0, 0><<<dim3(G4 / 128, (B_ * T_) / 128), 256, 0, stream>>>(
        ebf, T_, (long)S_ * E_, (long)E_, Wihb, bsum, nullptr, 1,
        Xg, G4, E_);

    // persistent scan: W fully resident (LDS 36 rows transposed + VGPR 92 x2)
    size_t scan_smem = (size_t)NL2_ * 4096 + G4 * sizeof(float) + 128 * sizeof(uint);
    k_lstm_scan<<<B_, 512, scan_smem, stream>>>(Xg, WPu, hN, cN);

    // hhdec = hN @ W_hh^T + bsum (fp32, tiny)
    k_gemm<1, 0><<<dim3(G4 / 128, B_ / 64), 256, 0, stream>>>(
        hN, B_, 0L, (long)H_, W_hh, bsum, nullptr, 1,
        hhdec, B_, G4, H_);

    // Gdec = e_tgt @ W_ih^T + hhdec[b]  (bf16 out; decoder is non-recurrent)
    k_gemm_mfma<0, 1><<<dim3(G4 / 128, (B_ * T_) / 128), 256, 0, stream>>>(
        ebf + T_ * E_, T_, (long)S_ * E_, (long)E_, Wihb, nullptr, hhdec, T_,
        Gdecb, G4, E_);

    // decode cell (bf16 in) -> hdec_bf
    k_dec_cell<<<(B_ * T_ * H_) / 256, 256, 0, stream>>>(Gdecb, cN, hdec_bf);

    // z1 = relu(hdec @ W1 + b1) -> bf16
    k_gemm_mfma<1, 1><<<dim3(P1_ / 128, (B_ * T_) / 128), 256, 0, stream>>>(
        hdec_bf, B_ * T_, 0L, (long)H_, W1T, b1, nullptr, 1,
        z1b, P1_, H_);

    // z2 = relu(z1 @ W2 + b2) -> f32
    k_gemm_mfma<1, 0><<<dim3(P2_ / 128, (B_ * T_) / 128), 256, 0, stream>>>(
        z1b, B_ * T_, 0L, (long)P1_, W2T, b2, nullptr, 1,
        z2, P2_, P1_);

    // out = sigmoid(z2 . W3 + b3)
    k_mlp3<<<(B_ * T_) / 4, 256, 0, stream>>>(z2, W3, b3, out);
}

// Round 13
// 423.209 us; speedup vs baseline: 1.3827x; 1.1190x over previous
//
#include <hip/hip_runtime.h>
#include <hip/hip_bf16.h>
#include <math.h>

#define B_  256
#define S_  200
#define F_  10
#define T_  100
#define E_  128
#define H_  256
#define G4  1024   // 4*H
#define P1_ 512
#define P2_ 128

typedef __attribute__((ext_vector_type(8))) short short8;
typedef __attribute__((ext_vector_type(4))) float f32x4;
typedef _Float16 half2f __attribute__((ext_vector_type(2)));

#if __has_builtin(__builtin_amdgcn_fdot2)
#define FDOT2(w2, h2, acc) __builtin_amdgcn_fdot2((w2), (h2), (acc), false)
#else
#define FDOT2(w2, h2, acc) ((acc) + (float)((w2)[0]) * (float)((h2)[0]) + (float)((w2)[1]) * (float)((h2)[1]))
#endif
#define BCH2(u) __builtin_bit_cast(half2f, (u))

// scan W placement (kpair rows of 1024 uints): 36 in LDS, 92 in VGPRs (x2 cols)
#define NL2_ 36
#define NV2_ 92

__device__ __forceinline__ float sigf(float x) { return 1.0f / (1.0f + expf(-x)); }
__device__ __forceinline__ float bf2f(ushort u) { return __uint_as_float(((uint)u) << 16); }
__device__ __forceinline__ ushort f2bf(float f) {
    __hip_bfloat16 v = __float2bfloat16(f);
    return *(ushort*)&v;
}
__device__ __forceinline__ ushort f2h(float f) {
    _Float16 h = (_Float16)f;
    return __builtin_bit_cast(ushort, h);
}
__device__ __forceinline__ float h2f(ushort u) {
    return (float)__builtin_bit_cast(_Float16, u);
}

__global__ __launch_bounds__(256) void k_bsum(const float* __restrict__ bi,
                                              const float* __restrict__ bh,
                                              float* __restrict__ bs) {
    int i = blockIdx.x * 256 + threadIdx.x;
    if (i < G4) bs[i] = bi[i] + bh[i];
}

// W (R x C) f32 -> WT (C x R) bf16. grid (C/32, R/32), 256 thr.
__global__ __launch_bounds__(256) void k_tr_bf16(const float* __restrict__ W,
                                                 ushort* __restrict__ WT,
                                                 int R, int C) {
    __shared__ float t[32][33];
    int c0 = blockIdx.x * 32, r0 = blockIdx.y * 32;
    int lc = threadIdx.x & 31, lr = threadIdx.x >> 5;
    #pragma unroll
    for (int i = 0; i < 4; ++i)
        t[lr + 8 * i][lc] = W[(long)(r0 + lr + 8 * i) * C + c0 + lc];
    __syncthreads();
    #pragma unroll
    for (int i = 0; i < 4; ++i)
        WT[(long)(c0 + lr + 8 * i) * R + r0 + lc] = f2bf(t[lc][lr + 8 * i]);
}

// W_hh (1024 x 256) f32 -> WPu: k-pair-interleaved fp16.
// WPu[kp*1024 + c] = pack(f16(W[c][2kp]), f16(W[c][2kp+1])), kp=0..127.
__global__ __launch_bounds__(256) void k_prep_wp(const float* __restrict__ W,
                                                 uint* __restrict__ WPu) {
    __shared__ float t[32][33];
    int k0 = blockIdx.x * 32, c0 = blockIdx.y * 32;
    int lk = threadIdx.x & 31, lc8 = threadIdx.x >> 5;
    #pragma unroll
    for (int i = 0; i < 4; ++i)
        t[lc8 + 8 * i][lk] = W[(long)(c0 + lc8 + 8 * i) * 256 + k0 + lk];
    __syncthreads();
    int kpl = threadIdx.x >> 4;   // 0..15
    int ccl = threadIdx.x & 15;   // 0..15
    #pragma unroll
    for (int hf = 0; hf < 2; ++hf) {
        int c = ccl + 16 * hf;
        uint lo = f2h(t[c][2 * kpl]);
        uint hi = f2h(t[c][2 * kpl + 1]);
        WPu[(long)(k0 / 2 + kpl) * G4 + c0 + c] = lo | (hi << 16);
    }
}

__global__ __launch_bounds__(256) void k_cvt_bf16(const float* __restrict__ W,
                                                  ushort* __restrict__ O, int n) {
    int i = blockIdx.x * 256 + threadIdx.x;
    if (i < n) O[i] = f2bf(W[i]);
}

// two (b,s) rows per block; 256 threads; bf16 out
__global__ __launch_bounds__(256) void k_gather(const int* __restrict__ x,
                                                const float* __restrict__ emb,
                                                ushort* __restrict__ e) {
    int bs = blockIdx.x * 2 + (threadIdx.x >> 7);
    int t  = threadIdx.x & 127;
    const int* xr = x + (long)bs * F_;
    float acc = 0.f;
    #pragma unroll
    for (int f = 0; f < F_; ++f) acc += emb[(long)xr[f] * E_ + t];
    e[(long)bs * E_ + t] = f2bf(acc * (1.0f / F_));
}

// ---------------- bf16 MFMA GEMM. OUTM: 0=f32, 1=bf16, 2=f16 ----------------
template<int ACT, int OUTM>
__global__ __launch_bounds__(256) void k_gemm_mfma(
    const ushort* __restrict__ A, int rowDiv, long sOuter, long sInner,
    const ushort* __restrict__ Bm,
    const float* __restrict__ bias,
    const float* __restrict__ rowAdd, int rowAddDiv,
    void* __restrict__ Cout, int N, int K)
{
    constexpr int LDT = 40;
    __shared__ ushort Al[128 * LDT];
    __shared__ ushort Bl[128 * LDT];
    int tid = threadIdx.x;
    int n0 = blockIdx.x * 128;
    int m0 = blockIdx.y * 128;

    int rA = tid >> 2, qA = tid & 3;
    int m_lo = m0 + rA, m_hi = m_lo + 64;
    long a0 = (long)(m_lo / rowDiv) * sOuter + (long)(m_lo % rowDiv) * sInner + qA * 8;
    long a1 = (long)(m_hi / rowDiv) * sOuter + (long)(m_hi % rowDiv) * sInner + qA * 8;
    const ushort* b0p = Bm + (long)(n0 + rA) * K + qA * 8;
    const ushort* b1p = Bm + (long)(n0 + rA + 64) * K + qA * 8;

    int lane = tid & 63, wave = tid >> 6;
    int wr = wave >> 1, wc = wave & 1;
    int lrow = lane & 15, lkh = lane >> 4;

    const f32x4 fz = {0.f, 0.f, 0.f, 0.f};
    f32x4 acc[4][4];
    #pragma unroll
    for (int i = 0; i < 4; ++i)
        #pragma unroll
        for (int j = 0; j < 4; ++j) acc[i][j] = fz;

    int nk = K >> 5;
    for (int kc = 0; kc < nk; ++kc) {
        uint4 va0 = *(const uint4*)(A + a0 + kc * 32);
        uint4 va1 = *(const uint4*)(A + a1 + kc * 32);
        uint4 vb0 = *(const uint4*)(b0p + kc * 32);
        uint4 vb1 = *(const uint4*)(b1p + kc * 32);
        *(uint4*)&Al[rA * LDT + qA * 8]        = va0;
        *(uint4*)&Al[(rA + 64) * LDT + qA * 8] = va1;
        *(uint4*)&Bl[rA * LDT + qA * 8]        = vb0;
        *(uint4*)&Bl[(rA + 64) * LDT + qA * 8] = vb1;
        __syncthreads();
        short8 af[4], bfr[4];
        #pragma unroll
        for (int mi = 0; mi < 4; ++mi)
            af[mi] = *(const short8*)&Al[(wr * 64 + mi * 16 + lrow) * LDT + lkh * 8];
        #pragma unroll
        for (int ni = 0; ni < 4; ++ni)
            bfr[ni] = *(const short8*)&Bl[(wc * 64 + ni * 16 + lrow) * LDT + lkh * 8];
        #pragma unroll
        for (int mi = 0; mi < 4; ++mi)
            #pragma unroll
            for (int ni = 0; ni < 4; ++ni)
                acc[mi][ni] = __builtin_amdgcn_mfma_f32_16x16x32_bf16(
                    af[mi], bfr[ni], acc[mi][ni], 0, 0, 0);
        __syncthreads();
    }
    #pragma unroll
    for (int mi = 0; mi < 4; ++mi) {
        #pragma unroll
        for (int r = 0; r < 4; ++r) {
            int m = m0 + wr * 64 + mi * 16 + lkh * 4 + r;
            long rowoff = rowAdd ? (long)(m / rowAddDiv) * N : 0;
            #pragma unroll
            for (int ni = 0; ni < 4; ++ni) {
                int n = n0 + wc * 64 + ni * 16 + lrow;
                float v = acc[mi][ni][r];
                if (bias)   v += bias[n];
                if (rowAdd) v += rowAdd[rowoff + n];
                if (ACT)    v = fmaxf(v, 0.f);
                if (OUTM == 1)      ((ushort*)Cout)[(long)m * N + n] = f2bf(v);
                else if (OUTM == 2) ((ushort*)Cout)[(long)m * N + n] = f2h(v);
                else                ((float*)Cout)[(long)m * N + n] = v;
            }
        }
    }
}

// ---------------- z2 GEMM with fused mlp3 epilogue ----------------
// A = z1b (M,512) bf16; Bm = W2T (128,512) bf16. N=128 fixed (one tile).
// out[m] = sigmoid(dot(relu(z1@W2+b2), W3) + b3)
__global__ __launch_bounds__(256) void k_z2_fused(
    const ushort* __restrict__ A, const ushort* __restrict__ Bm,
    const float* __restrict__ b2, const float* __restrict__ W3,
    const float* __restrict__ b3, float* __restrict__ out)
{
    constexpr int LDT = 40;
    __shared__ ushort Al[128 * LDT];
    __shared__ ushort Bl[128 * LDT];
    __shared__ float Zl[128 * 132];
    int tid = threadIdx.x;
    int m0 = blockIdx.x * 128;
    const int K = P1_;

    int rA = tid >> 2, qA = tid & 3;
    const ushort* a0p = A + (long)(m0 + rA) * K + qA * 8;
    const ushort* a1p = A + (long)(m0 + rA + 64) * K + qA * 8;
    const ushort* b0p = Bm + (long)rA * K + qA * 8;
    const ushort* b1p = Bm + (long)(rA + 64) * K + qA * 8;

    int lane = tid & 63, wave = tid >> 6;
    int wr = wave >> 1, wc = wave & 1;
    int lrow = lane & 15, lkh = lane >> 4;

    const f32x4 fz = {0.f, 0.f, 0.f, 0.f};
    f32x4 acc[4][4];
    #pragma unroll
    for (int i = 0; i < 4; ++i)
        #pragma unroll
        for (int j = 0; j < 4; ++j) acc[i][j] = fz;

    for (int kc = 0; kc < K / 32; ++kc) {
        uint4 va0 = *(const uint4*)(a0p + kc * 32);
        uint4 va1 = *(const uint4*)(a1p + kc * 32);
        uint4 vb0 = *(const uint4*)(b0p + kc * 32);
        uint4 vb1 = *(const uint4*)(b1p + kc * 32);
        *(uint4*)&Al[rA * LDT + qA * 8]        = va0;
        *(uint4*)&Al[(rA + 64) * LDT + qA * 8] = va1;
        *(uint4*)&Bl[rA * LDT + qA * 8]        = vb0;
        *(uint4*)&Bl[(rA + 64) * LDT + qA * 8] = vb1;
        __syncthreads();
        short8 af[4], bfr[4];
        #pragma unroll
        for (int mi = 0; mi < 4; ++mi)
            af[mi] = *(const short8*)&Al[(wr * 64 + mi * 16 + lrow) * LDT + lkh * 8];
        #pragma unroll
        for (int ni = 0; ni < 4; ++ni)
            bfr[ni] = *(const short8*)&Bl[(wc * 64 + ni * 16 + lrow) * LDT + lkh * 8];
        #pragma unroll
        for (int mi = 0; mi < 4; ++mi)
            #pragma unroll
            for (int ni = 0; ni < 4; ++ni)
                acc[mi][ni] = __builtin_amdgcn_mfma_f32_16x16x32_bf16(
                    af[mi], bfr[ni], acc[mi][ni], 0, 0, 0);
        __syncthreads();
    }
    // stage relu(z2 + b2) tile into LDS
    #pragma unroll
    for (int mi = 0; mi < 4; ++mi) {
        #pragma unroll
        for (int r = 0; r < 4; ++r) {
            int row = wr * 64 + mi * 16 + lkh * 4 + r;
            #pragma unroll
            for (int ni = 0; ni < 4; ++ni) {
                int col = wc * 64 + ni * 16 + lrow;
                Zl[row * 132 + col] = fmaxf(acc[mi][ni][r] + b2[col], 0.f);
            }
        }
    }
    __syncthreads();
    // wave w reduces rows [w*32, w*32+32)
    float w3a = W3[lane], w3b = W3[64 + lane], b3v = b3[0];
    for (int r = 0; r < 32; ++r) {
        int row = wave * 32 + r;
        float s = Zl[row * 132 + lane] * w3a + Zl[row * 132 + 64 + lane] * w3b;
        #pragma unroll
        for (int off = 32; off > 0; off >>= 1) s += __shfl_down(s, off);
        if (lane == 0) out[m0 + row] = sigf(s + b3v);
    }
}

// Persistent LSTM scan, W fully CU-resident (r12 structure), Xg in fp16,
// 4-way split accumulator chains to break FDOT2 dependency stalls.
__global__ __launch_bounds__(512, 2) void k_lstm_scan(
    const ushort* __restrict__ Xgh, const uint* __restrict__ WPu,
    float* __restrict__ hN, float* __restrict__ cN, ushort* __restrict__ hNb)
{
    extern __shared__ __align__(16) char smem[];
    uint*   Wl    = (uint*)smem;                    // [1024 cols][NL2_ rows] uints
    float*  act_s = (float*)(smem + NL2_ * 4096);   // 1024 f32 (4 KB)
    uint*   h16u  = (uint*)(act_s + G4);            // 128 uints (packed f16 h)
    ushort* h16   = (ushort*)h16u;
    int tid = threadIdx.x;          // 0..511
    int b   = blockIdx.x;
    int cB  = tid + 512;

    // one-time LDS W fill, transposed (global read coalesced, LDS scatter)
    for (int i = tid; i < NL2_ * 1024; i += 512) {
        int row = i >> 10, col = i & 1023;
        Wl[col * NL2_ + row] = WPu[(long)row * G4 + col];
    }
    // one-time VGPR W fill (row-coalesced dword loads)
    uint wrA[NV2_], wrB[NV2_];
    #pragma unroll
    for (int i = 0; i < NV2_; ++i) {
        wrA[i] = WPu[(long)(NL2_ + i) * G4 + tid];
        wrB[i] = WPu[(long)(NL2_ + i) * G4 + cB];
    }
    if (tid < 128) h16u[tid] = 0;
    float c_r = 0.f;
    __syncthreads();

    int isTanhB = (tid >> 8) == 0;   // cB in [512,768) -> tanh; wave-uniform
    const ushort* xgp = Xgh + (long)b * T_ * G4;
    const uint* wcA = Wl + tid * NL2_;
    const uint* wcB = Wl + (tid + 512) * NL2_;

    for (int t = 0; t < T_; ++t) {
        float xvA = h2f(xgp[(long)t * G4 + tid]);
        float xvB = h2f(xgp[(long)t * G4 + cB]);
        float aA0 = 0.f, aA1 = 0.f, aB0 = 0.f, aB1 = 0.f;
        #pragma unroll
        for (int r4 = 0; r4 < NL2_ / 4; ++r4) {         // LDS rows: b128 x2
            uint4 hh = *(const uint4*)(h16u + 4 * r4);
            uint4 wa = *(const uint4*)(wcA + 4 * r4);
            uint4 wb = *(const uint4*)(wcB + 4 * r4);
            aA0 = FDOT2(BCH2(wa.x), BCH2(hh.x), aA0); aB0 = FDOT2(BCH2(wb.x), BCH2(hh.x), aB0);
            aA1 = FDOT2(BCH2(wa.y), BCH2(hh.y), aA1); aB1 = FDOT2(BCH2(wb.y), BCH2(hh.y), aB1);
            aA0 = FDOT2(BCH2(wa.z), BCH2(hh.z), aA0); aB0 = FDOT2(BCH2(wb.z), BCH2(hh.z), aB0);
            aA1 = FDOT2(BCH2(wa.w), BCH2(hh.w), aA1); aB1 = FDOT2(BCH2(wb.w), BCH2(hh.w), aB1);
        }
        #pragma unroll
        for (int r4 = 0; r4 < NV2_ / 4; ++r4) {         // VGPR rows (92)
            uint4 hh = *(const uint4*)(h16u + NL2_ + 4 * r4);
            aA0 = FDOT2(BCH2(wrA[4 * r4 + 0]), BCH2(hh.x), aA0);
            aB0 = FDOT2(BCH2(wrB[4 * r4 + 0]), BCH2(hh.x), aB0);
            aA1 = FDOT2(BCH2(wrA[4 * r4 + 1]), BCH2(hh.y), aA1);
            aB1 = FDOT2(BCH2(wrB[4 * r4 + 1]), BCH2(hh.y), aB1);
            aA0 = FDOT2(BCH2(wrA[4 * r4 + 2]), BCH2(hh.z), aA0);
            aB0 = FDOT2(BCH2(wrB[4 * r4 + 2]), BCH2(hh.z), aB0);
            aA1 = FDOT2(BCH2(wrA[4 * r4 + 3]), BCH2(hh.w), aA1);
            aB1 = FDOT2(BCH2(wrB[4 * r4 + 3]), BCH2(hh.w), aB1);
        }
        float aA = aA0 + aA1, aB = aB0 + aB1;
        act_s[tid] = sigf(aA + xvA);                    // cols 0..511: i,f gates
        float gB = aB + xvB;
        act_s[cB] = isTanhB ? tanhf(gB) : sigf(gB);     // cols 512..1023: g,o
        __syncthreads();
        if (tid < H_) {
            float cn = act_s[H_ + tid] * c_r + act_s[tid] * act_s[2 * H_ + tid];
            c_r = cn;
            float h = act_s[3 * H_ + tid] * tanhf(cn);
            h16[tid] = f2h(h);
            if (t == T_ - 1) {
                hN[(long)b * H_ + tid] = h;
                cN[(long)b * H_ + tid] = c_r;
                hNb[(long)b * H_ + tid] = f2bf(h);
            }
        }
        __syncthreads();
    }
}

// decode cell, bf16 gate input (Gdec written bf16 by MFMA GEMM)
__global__ __launch_bounds__(256) void k_dec_cell(const ushort* __restrict__ G,
                                                  const float* __restrict__ cNb,
                                                  ushort* __restrict__ hdec) {
    long idx = (long)blockIdx.x * 256 + threadIdx.x;
    int m = (int)(idx >> 8);
    int j = (int)(idx & 255);
    int b = m / T_;
    const ushort* g = G + (long)m * G4 + j;
    float gi = bf2f(g[0]), gf = bf2f(g[H_]);
    float gg = bf2f(g[2 * H_]), go = bf2f(g[3 * H_]);
    float cv = sigf(gf) * cNb[(long)b * H_ + j] + sigf(gi) * tanhf(gg);
    hdec[idx] = f2bf(sigf(go) * tanhf(cv));
}

extern "C" void kernel_launch(void* const* d_in, const int* in_sizes, int n_in,
                              void* d_out, int out_size, void* d_ws, size_t ws_size,
                              hipStream_t stream)
{
    const int*   x    = (const int*)d_in[0];
    const float* emb  = (const float*)d_in[1];
    const float* W_ih = (const float*)d_in[2];
    const float* W_hh = (const float*)d_in[3];
    const float* b_ih = (const float*)d_in[4];
    const float* b_hh = (const float*)d_in[5];
    const float* W1   = (const float*)d_in[6];
    const float* b1   = (const float*)d_in[7];
    const float* W2   = (const float*)d_in[8];
    const float* b2   = (const float*)d_in[9];
    const float* W3   = (const float*)d_in[10];
    const float* b3   = (const float*)d_in[11];
    float* out = (float*)d_out;

    float* ws = (float*)d_ws;
    ushort* ebf  = (ushort*)ws;                     // 6,553,600 ush
    ushort* Xgh  = (ushort*)(ws + 3276800);         // 26,214,400 ush (fp16 Xg)
    float* bsum  = ws + 3276800 + 13107200;         // 1024
    float* hN    = bsum + 1024;                     // 65,536
    float* cN    = hN + 65536;                      // 65,536
    ushort* hNb  = (ushort*)(cN + 65536);           // 65,536 ush
    float* hhdec = cN + 65536 + 32768;              // 262,144
    uint*  WPu   = (uint*)(hhdec + 262144);         // 131,072 uints
    ushort* Wihb = (ushort*)(WPu + 131072);         // 131,072 ush
    ushort* Whhb = Wihb + 131072;                   // 262,144 ush
    ushort* W1T  = Whhb + 262144;                   // 131,072 ush
    ushort* W2T  = W1T + 131072;                    // 65,536 ush
    // reuse (stream-ordered):
    ushort* Gdecb   = Xgh;                          // decoder gates bf16 (26.2M ush)
    ushort* hdec_bf = ebf;                          // after Gdec GEMM, ebf dead
    ushort* z1b     = Xgh;                          // after dec_cell, Gdecb dead

    k_bsum<<<4, 256, 0, stream>>>(b_ih, b_hh, bsum);
    k_prep_wp<<<dim3(8, 32), 256, 0, stream>>>(W_hh, WPu);
    k_tr_bf16<<<dim3(16, 8),  256, 0, stream>>>(W1, W1T, H_, P1_);
    k_tr_bf16<<<dim3(4, 16),  256, 0, stream>>>(W2, W2T, P1_, P2_);
    k_cvt_bf16<<<512, 256, 0, stream>>>(W_ih, Wihb, G4 * E_);
    k_cvt_bf16<<<1024, 256, 0, stream>>>(W_hh, Whhb, G4 * H_);
    k_gather<<<B_ * S_ / 2, 256, 0, stream>>>(x, emb, ebf);

    // Xg = e_hist @ W_ih^T + bsum  -> fp16 (feeds the scan)
    k_gemm_mfma<0, 2><<<dim3(G4 / 128, (B_ * T_) / 128), 256, 0, stream>>>(
        ebf, T_, (long)S_ * E_, (long)E_, Wihb, bsum, nullptr, 1,
        Xgh, G4, E_);

    // persistent scan: W fully resident; writes hN (f32), cN, hNb (bf16)
    size_t scan_smem = (size_t)NL2_ * 4096 + G4 * sizeof(float) + 128 * sizeof(uint);
    k_lstm_scan<<<B_, 512, scan_smem, stream>>>(Xgh, WPu, hN, cN, hNb);

    // hhdec = hN @ W_hh^T + bsum  (MFMA, M=256)
    k_gemm_mfma<0, 0><<<dim3(G4 / 128, B_ / 128), 256, 0, stream>>>(
        hNb, B_, 0L, (long)H_, Whhb, bsum, nullptr, 1,
        hhdec, G4, H_);

    // Gdec = e_tgt @ W_ih^T + hhdec[b]  (bf16 out; decoder is non-recurrent)
    k_gemm_mfma<0, 1><<<dim3(G4 / 128, (B_ * T_) / 128), 256, 0, stream>>>(
        ebf + T_ * E_, T_, (long)S_ * E_, (long)E_, Wihb, nullptr, hhdec, T_,
        Gdecb, G4, E_);

    // decode cell (bf16 in) -> hdec_bf
    k_dec_cell<<<(B_ * T_ * H_) / 256, 256, 0, stream>>>(Gdecb, cN, hdec_bf);

    // z1 = relu(hdec @ W1 + b1) -> bf16
    k_gemm_mfma<1, 1><<<dim3(P1_ / 128, (B_ * T_) / 128), 256, 0, stream>>>(
        hdec_bf, B_ * T_, 0L, (long)H_, W1T, b1, nullptr, 1,
        z1b, P1_, H_);

    // z2 GEMM + mlp3 fused -> out
    k_z2_fused<<<(B_ * T_) / 128, 256, 0, stream>>>(z1b, W2T, b2, W3, b3, out);
}